// Round 2
// baseline (84.570 us; speedup 1.0000x reference)
//
#include <hip/hip_runtime.h>

// out[b,v] = dot(OT[b, pid[v], :], W[v, :]) + bias[v]
// B=32, Q=180, H=768, V=19004. All fp32.
#define BB 32
#define QQ 180
#define HH 768
#define VV 19004
#define VB 64          // v's per chunk
#define HK 64          // h per staged chunk
#define NCH_H 6        // h-chunks per half (12 total, K-split x2)
#define MAXDESC 480
#define MAXGRID 960    // 2 * MAXDESC

// ---- ws layout (bytes) ----
// cnt:    0      (256 ints)
// cursor: 1024   (256 ints)
// ntot:   2048   (1 int)
// sorted: 4096   (19008 ints)
// desc:   80128  (480 int4)
// partial:87808  (2 * 32 * 19004 floats = 4.87 MB)

// ---------- pre-pass ----------
__global__ void count_k(const int* __restrict__ pid, int* __restrict__ cnt) {
    __shared__ int lc[QQ];
    for (int i = threadIdx.x; i < QQ; i += blockDim.x) lc[i] = 0;
    __syncthreads();
    for (int v = blockIdx.x * blockDim.x + threadIdx.x; v < VV;
         v += gridDim.x * blockDim.x)
        atomicAdd(&lc[pid[v]], 1);
    __syncthreads();
    for (int i = threadIdx.x; i < QQ; i += blockDim.x) {
        int c = lc[i];
        if (c) atomicAdd(&cnt[i], c);
    }
}

__global__ void scan_desc_k(const int* __restrict__ cnt, int* __restrict__ cursor,
                            int4* __restrict__ desc, int* __restrict__ ntot) {
    __shared__ int sc[256];
    __shared__ int sn[256];
    const int t = threadIdx.x;
    const int c = (t < QQ) ? cnt[t] : 0;
    sc[t] = c;
    __syncthreads();
    for (int off = 1; off < 256; off <<= 1) {
        int add = (t >= off) ? sc[t - off] : 0;
        __syncthreads();
        sc[t] += add;
        __syncthreads();
    }
    const int qstart = sc[t] - c;
    if (t < QQ) cursor[t] = qstart;
    const int nch = (c + VB - 1) / VB;
    sn[t] = nch;
    __syncthreads();
    for (int off = 1; off < 256; off <<= 1) {
        int add = (t >= off) ? sn[t - off] : 0;
        __syncthreads();
        sn[t] += add;
        __syncthreads();
    }
    const int cb = sn[t] - nch;
    if (t < QQ) {
        for (int j = 0; j < nch; ++j)
            desc[cb + j] = make_int4(t, qstart + j * VB, min(VB, c - j * VB), 0);
    }
    if (t == 255) *ntot = sn[255];
}

__global__ void scatter_k(const int* __restrict__ pid, int* __restrict__ cursor,
                          int* __restrict__ sorted) {
    for (int v = blockIdx.x * blockDim.x + threadIdx.x; v < VV;
         v += gridDim.x * blockDim.x) {
        int q = pid[v];
        int pos = atomicAdd(&cursor[q], 1);
        sorted[pos] = v;
    }
}

// ---------- main: per-(chunk, h-half) tiled outer product ----------
// Block = 128 threads (2 waves). Thread t: l = t&15 -> v set {l, l+16, l+32, l+48};
// g = t>>4 -> b set {4g..4g+3}. 16 fp32 accumulators (4b x 4v).
// Per 4-h step: 4+4 ds_read_b128 feed 64 FMAs (2 B/FMA LDS traffic).
// Stride 68 (=64+4) pads: inner reads are 2-way bank aliased max (free, m136).
__launch_bounds__(128)
__global__ void main_k(const float* __restrict__ OT, const float* __restrict__ W,
                       const int* __restrict__ sorted, const int4* __restrict__ desc,
                       const int* __restrict__ ntot, float* __restrict__ partial) {
    const int nt = *ntot;
    const int bid = blockIdx.x;
    if (bid >= 2 * nt) return;
    const int ci = bid >> 1;
    const int half = bid & 1;
    const int4 d = desc[ci];
    const int q = d.x, start = d.y, len = d.z;
    const int h0 = half * (HH / 2);

    __shared__ float Wt[VB][HK + 4];
    __shared__ float OTt[BB][HK + 4];
    __shared__ int svs[VB];

    const int t = threadIdx.x;
    if (t < VB) svs[t] = sorted[start + ((t < len) ? t : 0)];
    __syncthreads();

    const int l = t & 15;
    const int g = t >> 4;  // 0..7: staging row sub-index AND b-group

    const float* wsrc[8];
#pragma unroll
    for (int p = 0; p < 8; ++p)
        wsrc[p] = W + (size_t)svs[p * 8 + g] * HH + h0 + l * 4;
    const float* osrc[4];
#pragma unroll
    for (int p = 0; p < 4; ++p)
        osrc[p] = OT + ((size_t)(p * 8 + g) * QQ + q) * HH + h0 + l * 4;

    float4 wr[8];
    float4 orr_[4];
#pragma unroll
    for (int p = 0; p < 8; ++p) wr[p] = *(const float4*)wsrc[p];
#pragma unroll
    for (int p = 0; p < 4; ++p) orr_[p] = *(const float4*)osrc[p];

    float acc[4][4];
#pragma unroll
    for (int j = 0; j < 4; ++j)
#pragma unroll
        for (int k = 0; k < 4; ++k) acc[j][k] = 0.f;

    for (int c = 0; c < NCH_H; ++c) {
        __syncthreads();
#pragma unroll
        for (int p = 0; p < 8; ++p) *(float4*)&Wt[p * 8 + g][l * 4] = wr[p];
#pragma unroll
        for (int p = 0; p < 4; ++p) *(float4*)&OTt[p * 8 + g][l * 4] = orr_[p];
        __syncthreads();
        if (c + 1 < NCH_H) {
            const int off = (c + 1) * HK;
#pragma unroll
            for (int p = 0; p < 8; ++p) wr[p] = *(const float4*)(wsrc[p] + off);
#pragma unroll
            for (int p = 0; p < 4; ++p) orr_[p] = *(const float4*)(osrc[p] + off);
        }
#pragma unroll
        for (int s = 0; s < 16; ++s) {
            float4 w[4];
#pragma unroll
            for (int k = 0; k < 4; ++k)
                w[k] = *(const float4*)&Wt[l + 16 * k][s * 4];
#pragma unroll
            for (int j = 0; j < 4; ++j) {
                const float4 o = *(const float4*)&OTt[4 * g + j][s * 4];
#pragma unroll
                for (int k = 0; k < 4; ++k) {
                    acc[j][k] = fmaf(o.x, w[k].x, acc[j][k]);
                    acc[j][k] = fmaf(o.y, w[k].y, acc[j][k]);
                    acc[j][k] = fmaf(o.z, w[k].z, acc[j][k]);
                    acc[j][k] = fmaf(o.w, w[k].w, acc[j][k]);
                }
            }
        }
    }

    float* P = partial + (size_t)half * BB * VV;
#pragma unroll
    for (int k = 0; k < 4; ++k) {
        const int vi = l + 16 * k;
        if (vi < len) {
            const int v = svs[vi];
#pragma unroll
            for (int j = 0; j < 4; ++j)
                P[(size_t)(4 * g + j) * VV + v] = acc[j][k];
        }
    }
}

// ---------- final combine ----------
__global__ void reduce_k(const float* __restrict__ partial,
                         const float* __restrict__ bias, float* __restrict__ out) {
    const int i = blockIdx.x * blockDim.x + threadIdx.x;
    if (i >= BB * VV) return;
    const int v = i % VV;
    out[i] = partial[i] + partial[BB * VV + i] + bias[v];
}

extern "C" void kernel_launch(void* const* d_in, const int* in_sizes, int n_in,
                              void* d_out, int out_size, void* d_ws, size_t ws_size,
                              hipStream_t stream) {
    const float* OT   = (const float*)d_in[0];  // [B,Q,H]
    const float* W    = (const float*)d_in[1];  // [V,H]
    const float* bias = (const float*)d_in[2];  // [V]
    const int*   pid  = (const int*)d_in[3];    // [V]
    float* out = (float*)d_out;                 // [B,V]

    char* ws = (char*)d_ws;
    int*   cnt     = (int*)(ws + 0);
    int*   cursor  = (int*)(ws + 1024);
    int*   ntot    = (int*)(ws + 2048);
    int*   sorted  = (int*)(ws + 4096);
    int4*  desc    = (int4*)(ws + 80128);
    float* partial = (float*)(ws + 87808);

    hipMemsetAsync(cnt, 0, 256 * sizeof(int), stream);
    count_k<<<80, 256, 0, stream>>>(pid, cnt);
    scan_desc_k<<<1, 256, 0, stream>>>(cnt, cursor, desc, ntot);
    scatter_k<<<80, 256, 0, stream>>>(pid, cursor, sorted);

    main_k<<<MAXGRID, 128, 0, stream>>>(OT, W, sorted, desc, ntot, partial);

    const int n = BB * VV;
    reduce_k<<<(n + 255) / 256, 256, 0, stream>>>(partial, bias, out);
}